// Round 6
// baseline (1340.686 us; speedup 1.0000x reference)
//
#include <hip/hip_runtime.h>
#include <type_traits>

typedef __attribute__((ext_vector_type(8))) short short8;
typedef __attribute__((ext_vector_type(4))) float float4v;

__device__ inline float bf2f(short s) {
    unsigned u = ((unsigned)(unsigned short)s) << 16;
    float f; __builtin_memcpy(&f, &u, 4); return f;
}
__device__ inline short f2bf(float f) {
    unsigned u; __builtin_memcpy(&u, &f, 4);
    unsigned lsb = (u >> 16) & 1;
    u += 0x7fffu + lsb;
    return (short)(u >> 16);
}

// ---------------------------------------------------------------------------
// Transpose + convert: in f32 (K x ldn), column slice [noff, noff+Ntile) ->
// out bf16 (Ntile x K). 64x64 tiles.
// ---------------------------------------------------------------------------
__global__ __launch_bounds__(256) void transpose_conv(const float* __restrict__ in,
                                                      short* __restrict__ out,
                                                      int K, int ldn, int noff) {
    __shared__ float t[64 * 65];
    const int n0 = blockIdx.x * 64, k0 = blockIdx.y * 64;
    const int tid = threadIdx.x;
#pragma unroll
    for (int i = 0; i < 4; i++) {
        int slot = tid + 256 * i;
        int row = slot >> 4, c4 = slot & 15;  // row: k, c4: n-chunk of 4
        float4v v = *(const float4v*)(in + (size_t)(k0 + row) * ldn + noff + n0 + c4 * 4);
#pragma unroll
        for (int j = 0; j < 4; j++) t[row * 65 + c4 * 4 + j] = v[j];
    }
    __syncthreads();
#pragma unroll
    for (int i = 0; i < 2; i++) {
        int slot = tid + 256 * i;
        int row = slot >> 3, c8 = slot & 7;  // row: n, c8: k-chunk of 8
        short8 v;
#pragma unroll
        for (int j = 0; j < 8; j++) v[j] = f2bf(t[(c8 * 8 + j) * 65 + row]);
        *(short8*)(out + (size_t)(n0 + row) * K + k0 + c8 * 8) = v;
    }
}

// ---------------------------------------------------------------------------
// bf16 transpose: in (K x N) -> out (N x K), 64x64 tiles (for V -> V^T)
// ---------------------------------------------------------------------------
__global__ __launch_bounds__(256) void transpose_k(const short* __restrict__ in,
                                                   short* __restrict__ out,
                                                   int K, int N) {
    __attribute__((aligned(16))) __shared__ short t[64 * 72];
    const int n0 = blockIdx.x * 64, k0 = blockIdx.y * 64;
    const int tid = threadIdx.x;
#pragma unroll
    for (int i = 0; i < 2; i++) {
        int slot = tid + 256 * i;
        int row = slot >> 3, c8 = slot & 7;
        *(short8*)&t[row * 72 + c8 * 8] =
            *(const short8*)(in + (size_t)(k0 + row) * N + n0 + c8 * 8);
    }
    __syncthreads();
#pragma unroll
    for (int i = 0; i < 2; i++) {
        int slot = tid + 256 * i;
        int row = slot >> 3, c8 = slot & 7;
        short8 v;
#pragma unroll
        for (int j = 0; j < 8; j++) v[j] = t[(c8 * 8 + j) * 72 + row];
        *(short8*)(out + (size_t)(n0 + row) * K + k0 + c8 * 8) = v;
    }
}

// ---------------------------------------------------------------------------
// GEMM: C(:, coff + [0,Nt)) = A (MxK) * Bt^T,  Bt (Nt x K) bf16, C ld = ldc.
// A: float (converted to bf16 during staging) or bf16 (short).
// C: bf16 (short, f2bf) or float (raw f32 store — for the final output).
// 128x128 tile, BK=64, 4 waves 2x2, each wave 64x64 = 4x4 MFMA tiles.
// ---------------------------------------------------------------------------
#define LDK 72

template <typename AT, typename CT>
__global__ __launch_bounds__(256) void gemm_bt_128(const AT* __restrict__ A,
                                                   const short* __restrict__ Bt,
                                                   CT* __restrict__ C,
                                                   int K, int ldc, int coff) {
    __attribute__((aligned(16))) __shared__ short As[128 * LDK];
    __attribute__((aligned(16))) __shared__ short Bs[128 * LDK];
    const int tid = threadIdx.x;
    const int lane = tid & 63, wave = tid >> 6;
    const int quad = lane >> 4, l16 = lane & 15;
    const int wr = wave >> 1, wc = wave & 1;
    const int m0 = blockIdx.y * 128, n0 = blockIdx.x * 128;

    float4v acc[4][4];
#pragma unroll
    for (int i = 0; i < 4; i++)
#pragma unroll
        for (int j = 0; j < 4; j++) acc[i][j] = (float4v){0.f, 0.f, 0.f, 0.f};

    for (int k0 = 0; k0 < K; k0 += 64) {
#pragma unroll
        for (int i = 0; i < 4; i++) {
            int slot = tid + 256 * i;
            int row = slot >> 3, c8 = slot & 7;
            if constexpr (std::is_same<AT, float>::value) {
                const float* src = A + (size_t)(m0 + row) * K + k0 + c8 * 8;
                float4v a = *(const float4v*)src;
                float4v b = *(const float4v*)(src + 4);
                short8 o;
#pragma unroll
                for (int j = 0; j < 4; j++) { o[j] = f2bf(a[j]); o[4 + j] = f2bf(b[j]); }
                *(short8*)&As[row * LDK + c8 * 8] = o;
            } else {
                *(short8*)&As[row * LDK + c8 * 8] =
                    *(const short8*)(A + (size_t)(m0 + row) * K + k0 + c8 * 8);
            }
        }
#pragma unroll
        for (int i = 0; i < 4; i++) {
            int slot = tid + 256 * i;
            int row = slot >> 3, c8 = slot & 7;
            *(short8*)&Bs[row * LDK + c8 * 8] =
                *(const short8*)(Bt + (size_t)(n0 + row) * K + k0 + c8 * 8);
        }
        __syncthreads();
#pragma unroll
        for (int kc = 0; kc < 2; kc++) {
            short8 afr[4], bfr[4];
#pragma unroll
            for (int rt = 0; rt < 4; rt++)
                afr[rt] = *(const short8*)&As[(wr * 64 + rt * 16 + l16) * LDK + kc * 32 + quad * 8];
#pragma unroll
            for (int ct = 0; ct < 4; ct++)
                bfr[ct] = *(const short8*)&Bs[(wc * 64 + ct * 16 + l16) * LDK + kc * 32 + quad * 8];
#pragma unroll
            for (int rt = 0; rt < 4; rt++)
#pragma unroll
                for (int ct = 0; ct < 4; ct++)
                    acc[rt][ct] = __builtin_amdgcn_mfma_f32_16x16x32_bf16(
                        afr[rt], bfr[ct], acc[rt][ct], 0, 0, 0);
        }
        __syncthreads();
    }
    // C layout: col = lane&15, row = quad*4 + reg
#pragma unroll
    for (int rt = 0; rt < 4; rt++)
#pragma unroll
        for (int ct = 0; ct < 4; ct++) {
            int col = coff + n0 + wc * 64 + ct * 16 + l16;
#pragma unroll
            for (int r = 0; r < 4; r++) {
                int row = m0 + wr * 64 + rt * 16 + quad * 4 + r;
                if constexpr (std::is_same<CT, float>::value)
                    C[(size_t)row * ldc + col] = acc[rt][ct][r];
                else
                    C[(size_t)row * ldc + col] = f2bf(acc[rt][ct][r]);
            }
        }
}

// ---------------------------------------------------------------------------
// RoPE (interleaved pairs), in-place on (S, nheads*128) bf16; freqs f32.
// ---------------------------------------------------------------------------
__global__ void rope_kernel(short* __restrict__ T, const float* __restrict__ cosb,
                            const float* __restrict__ sinb, int nheads) {
    int idx = blockIdx.x * 256 + threadIdx.x;
    int total = 2048 * nheads * 16;
    if (idx >= total) return;
    int chunk = idx & 15;
    int t2 = idx >> 4;
    int hh = t2 % nheads;
    int s = t2 / nheads;
    short* p = T + ((size_t)s * nheads + hh) * 128 + chunk * 8;
    short8 v = *(short8*)p;
    short8 o;
#pragma unroll
    for (int t = 0; t < 4; t++) {
        int i = chunk * 4 + t;
        float c = cosb[s * 64 + i];
        float sn = sinb[s * 64 + i];
        float a = bf2f(v[2 * t]), b = bf2f(v[2 * t + 1]);
        o[2 * t] = f2bf(a * c - b * sn);
        o[2 * t + 1] = f2bf(a * sn + b * c);
    }
    *(short8*)p = o;
}

// ---------------------------------------------------------------------------
// Flash attention: 1 block = (64 q rows, 1 head); 4 waves x 16 rows.
// Q: (2048, 32*128); K: (2048, 8*128); Vt: (8*128, 2048) pre-transposed.
// O may alias Q (block reads exactly the cells it later writes).
// ---------------------------------------------------------------------------
__global__ __launch_bounds__(256) void attn_kernel(const short* __restrict__ Q,
                                                   const short* __restrict__ K,
                                                   const short* __restrict__ Vt,
                                                   short* __restrict__ O) {
    __attribute__((aligned(16))) __shared__ short Ks[32 * 136];
    __attribute__((aligned(16))) __shared__ short Vs[128 * 40];
    __attribute__((aligned(16))) __shared__ short Ps[4][16 * 40];
    const int tid = threadIdx.x;
    const int lane = tid & 63, wave = tid >> 6;
    const int quad = lane >> 4, l16 = lane & 15;
    const int h = blockIdx.y, kvh = h >> 2;
    const int qbase = blockIdx.x * 64;
    const int q0 = qbase + wave * 16;

    short8 qf[4];
    const short* qrow = Q + (size_t)(q0 + l16) * 4096 + h * 128;
#pragma unroll
    for (int ks = 0; ks < 4; ks++) qf[ks] = *(const short8*)(qrow + ks * 32 + quad * 8);

    float4v o_acc[8];
#pragma unroll
    for (int i = 0; i < 8; i++) o_acc[i] = (float4v){0.f, 0.f, 0.f, 0.f};
    float m_i[4], l_i[4];
#pragma unroll
    for (int r = 0; r < 4; r++) { m_i[r] = -1e9f; l_i[r] = 0.f; }
    const float scale = 0.08838834764831845f;  // 1/sqrt(128)

    const int kv_end = qbase + 64;
    for (int kv0 = 0; kv0 < kv_end; kv0 += 32) {
#pragma unroll
        for (int i = 0; i < 2; i++) {
            int slot = tid + 256 * i;
            int row = slot >> 4, c8 = slot & 15;
            *(short8*)&Ks[row * 136 + c8 * 8] =
                *(const short8*)(K + (size_t)(kv0 + row) * 1024 + kvh * 128 + c8 * 8);
        }
#pragma unroll
        for (int i = 0; i < 2; i++) {
            int slot = tid + 256 * i;
            int d = slot >> 2, c4 = slot & 3;
            *(short8*)&Vs[d * 40 + c4 * 8] =
                *(const short8*)(Vt + (size_t)(kvh * 128 + d) * 2048 + kv0 + c4 * 8);
        }
        __syncthreads();

        if (kv0 <= q0 + 15) {
            float4v s_acc[2];
            s_acc[0] = (float4v){0.f, 0.f, 0.f, 0.f};
            s_acc[1] = (float4v){0.f, 0.f, 0.f, 0.f};
#pragma unroll
            for (int nsub = 0; nsub < 2; nsub++)
#pragma unroll
                for (int ks = 0; ks < 4; ks++) {
                    short8 kf = *(const short8*)&Ks[(nsub * 16 + l16) * 136 + ks * 32 + quad * 8];
                    s_acc[nsub] = __builtin_amdgcn_mfma_f32_16x16x32_bf16(
                        qf[ks], kf, s_acc[nsub], 0, 0, 0);
                }
            float p[2][4];
#pragma unroll
            for (int nsub = 0; nsub < 2; nsub++)
#pragma unroll
                for (int r = 0; r < 4; r++) {
                    int row = q0 + quad * 4 + r;
                    int col = kv0 + nsub * 16 + l16;
                    float v = s_acc[nsub][r] * scale;
                    p[nsub][r] = (col <= row) ? v : -1e9f;
                }
            float tm[4];
#pragma unroll
            for (int r = 0; r < 4; r++) tm[r] = fmaxf(p[0][r], p[1][r]);
#pragma unroll
            for (int off = 1; off < 16; off <<= 1)
#pragma unroll
                for (int r = 0; r < 4; r++)
                    tm[r] = fmaxf(tm[r], __shfl_xor(tm[r], off, 64));
            float alpha[4], rs[4];
#pragma unroll
            for (int r = 0; r < 4; r++) {
                float mn = fmaxf(m_i[r], tm[r]);
                alpha[r] = __expf(m_i[r] - mn);
                m_i[r] = mn;
                rs[r] = 0.f;
            }
#pragma unroll
            for (int nsub = 0; nsub < 2; nsub++)
#pragma unroll
                for (int r = 0; r < 4; r++) {
                    float e = __expf(p[nsub][r] - m_i[r]);
                    rs[r] += e;
                    Ps[wave][(quad * 4 + r) * 40 + nsub * 16 + l16] = f2bf(e);
                }
#pragma unroll
            for (int off = 1; off < 16; off <<= 1)
#pragma unroll
                for (int r = 0; r < 4; r++) rs[r] += __shfl_xor(rs[r], off, 64);
#pragma unroll
            for (int r = 0; r < 4; r++) l_i[r] = l_i[r] * alpha[r] + rs[r];
#pragma unroll
            for (int dt = 0; dt < 8; dt++)
#pragma unroll
                for (int r = 0; r < 4; r++) o_acc[dt][r] *= alpha[r];
            short8 pf = *(const short8*)&Ps[wave][l16 * 40 + quad * 8];
#pragma unroll
            for (int dt = 0; dt < 8; dt++) {
                short8 vf = *(const short8*)&Vs[(dt * 16 + l16) * 40 + quad * 8];
                o_acc[dt] = __builtin_amdgcn_mfma_f32_16x16x32_bf16(pf, vf, o_acc[dt], 0, 0, 0);
            }
        }
        __syncthreads();
    }
#pragma unroll
    for (int dt = 0; dt < 8; dt++)
#pragma unroll
        for (int r = 0; r < 4; r++) {
            int row = q0 + quad * 4 + r;
            O[(size_t)row * 4096 + h * 128 + dt * 16 + l16] = f2bf(o_acc[dt][r] / l_i[r]);
        }
}

// ---------------------------------------------------------------------------
// Workspace (36 MB peak):
//   WT  [ 0, 8) MB — bf16 transposed weight slice (<=1024 cols at a time)
//   Qb  [ 8,24) MB — Q (roped), then attention output in place
//   Kb  [24,28) MB
//   Vb  [28,32) MB
//   Vt  [32,36) MB
// d_out is FLOAT32 (2048x4096 f32) — established round 5 post-mortem.
// ---------------------------------------------------------------------------
extern "C" void kernel_launch(void* const* d_in, const int* in_sizes, int n_in,
                              void* d_out, int out_size, void* d_ws, size_t ws_size,
                              hipStream_t stream) {
    (void)in_sizes; (void)n_in; (void)out_size; (void)ws_size;
    const float* x  = (const float*)d_in[0];
    const float* wq = (const float*)d_in[1];
    const float* wk = (const float*)d_in[2];
    const float* wv = (const float*)d_in[3];
    const float* wo = (const float*)d_in[4];
    const float* fc = (const float*)d_in[5];
    const float* fs = (const float*)d_in[6];
    float* out = (float*)d_out;
    char* ws = (char*)d_ws;

    short* WT = (short*)(ws);
    short* Qb = (short*)(ws + (8ull << 20));
    short* Kb = (short*)(ws + (24ull << 20));
    short* Vb = (short*)(ws + (28ull << 20));
    short* Vt = (short*)(ws + (32ull << 20));

    // Q = x @ wq, in 1024-column slices
    for (int s = 0; s < 4; s++) {
        transpose_conv<<<dim3(16, 64), 256, 0, stream>>>(wq, WT, 4096, 4096, s * 1024);
        gemm_bt_128<float, short><<<dim3(8, 16), 256, 0, stream>>>(x, WT, Qb, 4096, 4096, s * 1024);
    }
    // K, V
    transpose_conv<<<dim3(16, 64), 256, 0, stream>>>(wk, WT, 4096, 1024, 0);
    gemm_bt_128<float, short><<<dim3(8, 16), 256, 0, stream>>>(x, WT, Kb, 4096, 1024, 0);
    transpose_conv<<<dim3(16, 64), 256, 0, stream>>>(wv, WT, 4096, 1024, 0);
    gemm_bt_128<float, short><<<dim3(8, 16), 256, 0, stream>>>(x, WT, Vb, 4096, 1024, 0);

    rope_kernel<<<dim3(2048 * 32 * 16 / 256), 256, 0, stream>>>(Qb, fc, fs, 32);
    rope_kernel<<<dim3(2048 * 8 * 16 / 256), 256, 0, stream>>>(Kb, fc, fs, 8);

    transpose_k<<<dim3(16, 32), 256, 0, stream>>>(Vb, Vt, 2048, 1024);
    attn_kernel<<<dim3(32, 32), 256, 0, stream>>>(Qb, Kb, Vt, Qb);

    // out (f32) = attn @ wo, in 1024-column slices
    for (int s = 0; s < 4; s++) {
        transpose_conv<<<dim3(16, 64), 256, 0, stream>>>(wo, WT, 4096, 4096, s * 1024);
        gemm_bt_128<short, float><<<dim3(8, 16), 256, 0, stream>>>(Qb, WT, out, 4096, 4096, s * 1024);
    }
}